// Round 2
// baseline (59.330 us; speedup 1.0000x reference)
//
#include <hip/hip_runtime.h>
#include <math.h>

#define DD     64
#define RPB    16    // rows per block = MFMA tile M (one tile, 4 waves share it)
#define N_BF16 13    // r19-verified: absmax identical at 14 and 13 (= 2^-8 bf16
                     // quantization floor) => convergence error below floor.
                     // Do NOT drop to 12: ~0.13us gain vs FAIL risk.
#define N_POL  2     // split-precision polish applies
#define ZS     72    // shorts per z-image row (144 B: 16B-aligned row stride)

typedef float f4 __attribute__((ext_vector_type(4)));
typedef short s4 __attribute__((ext_vector_type(4)));   // 4 bf16 = 8 B (b64)
typedef short s8 __attribute__((ext_vector_type(8)));   // 8 bf16 = 4 VGPRs

// lambda = 2*log2(e) is PRE-SCALED into W and x, so the MFMA result is already
// the exp2 argument: tanh(a) = 1 - 2/(exp2(lam*a)+1). Removes one VALU mul
// from every tanh's dependent chain. |lam*zl| <= ~40 -> exp2 in range.
__device__ __forceinline__ float tanh_pre(float e_arg) {
    const float e = __builtin_amdgcn_exp2f(e_arg);
    return fmaf(-2.0f, __builtin_amdgcn_rcpf(e + 1.0f), 1.0f);
}
__device__ __forceinline__ unsigned short f2bf(float f) {
    return (unsigned short)((__float_as_uint(f) + 0x8000u) >> 16);
}
__device__ __forceinline__ float bf2f(unsigned short h) {
    return __uint_as_float(((unsigned int)h) << 16);
}
__device__ __forceinline__ s4 pack4bf(float a, float b, float c, float d) {
    s4 r;
    r[0] = (short)f2bf(a); r[1] = (short)f2bf(b);
    r[2] = (short)f2bf(c); r[3] = (short)f2bf(d);
    return r;
}

// COLUMN-SPLIT MFMA, OPERAND-SWAPPED (r20): one block = one 16-row tile, FOUR
// waves (one per SIMD) each owning 16 output columns (spreads the per-row
// tanhs across 4 SIMDs — fused-pair / single-wave alternatives costed and
// lose on serialized quarter-rate transcendentals).
//
// r20 delta: MFMA operands SWAPPED — D = W'.z^T instead of z.W'^T. A-frag =
// W' (unchanged register content: A[m=lane&15 -> out-col][k=(lane>>4)*8+j]);
// B-frag = z image, read with the IDENTICAL ds_read_b128 addressing as the
// old A-frag (A/B share the lane->(idx,k) layout). C/D now maps to
// n(=lane&15) = batch row, m(=(lane>>4)*4+reg) = out col -> each lane holds
// ONE batch row x 4 CONSECUTIVE cols. Consequences, all vectorizing:
//   - z writeback: 1 ds_write_b64 (was 4 scattered ds_write_b16)
//   - x load:      1 float4      (was 4 scalar dwords at 256B stride)
//   - out store:   1 float4      (was 4 scattered dwords)
// Bank check: b64 write bank=(4c0+2q+8t)%32 -> 2-way only = free (m136).
__global__ __launch_bounds__(256)
void tanh_newton_mfma(const float* __restrict__ x,
                      const float* __restrict__ W,
                      float* __restrict__ out)
{
    __shared__ alignas(16) short zbuf[2][16 * ZS];  // bf16 hi image, dbuf
    __shared__ alignas(16) short zLo[2][16 * ZS];   // polish lo image, dbuf

    const int lane = threadIdx.x & 63;
    const int t    = threadIdx.x >> 6;    // wave id = column tile 0..3
    const int c0   = lane & 15;           // r20: this lane's BATCH ROW in tile
    const int q    = lane >> 4;
    const int r0   = blockIdx.x * RPB;
    const int wcol = 16 * t + 4 * q;      // first of this lane's 4 out cols

    const float LAM = 2.885390081777927f; // 2*log2(e), folded into W and x

    // ---- W fragments (A-operand): lane m=c0 -> out col 16t+c0, k=8q+j.
    // Register content identical to pre-swap kernel. bf16 hi+lo of LAM*W.
    s8 whi[2], wlo[2];
#pragma unroll
    for (int h = 0; h < 2; ++h) {
        const float* wp = W + (16 * t + c0) * DD + 8 * q + 32 * h;
        const float4 u = *reinterpret_cast<const float4*>(wp);
        const float4 v = *reinterpret_cast<const float4*>(wp + 4);
        const float wf[8] = {u.x, u.y, u.z, u.w, v.x, v.y, v.z, v.w};
        s8 hi8, lo8;
#pragma unroll
        for (int j = 0; j < 8; ++j) {
            const float ws = LAM * wf[j];
            const unsigned short hb = f2bf(ws);
            hi8[j] = (short)hb;
            lo8[j] = (short)f2bf(ws - bf2f(hb));
        }
        whi[h] = hi8;
        wlo[h] = lo8;
    }

    // ---- x fragment (new C layout: batch row c0, cols wcol..wcol+3) ----
    // One coalesced float4 load (16B aligned: wcol*4 is a multiple of 16).
    f4 xf;
    float z[4];
    {
        const float4 xv = *reinterpret_cast<const float4*>(
            x + (r0 + c0) * DD + wcol);
        xf[0] = LAM * xv.x; xf[1] = LAM * xv.y;
        xf[2] = LAM * xv.z; xf[3] = LAM * xv.w;
#pragma unroll
        for (int i = 0; i < 4; ++i) z[i] = tanh_pre(xf[i]);
    }

    const f4 zero = {0.f, 0.f, 0.f, 0.f};

    // ---- phase 1: fixed-count bf16 MFMA applies, 1 barrier each.
    // Buffer-parity safety: apply it reads zbuf[it&1]; its reads complete
    // (hw waitcnt before MFMA) before it reaches apply it+1's barrier, which
    // precedes any it+2 write to the same buffer.
    for (int it = 0; it < N_BF16; ++it) {
        const int sel = it & 1;
        *reinterpret_cast<s4*>(&zbuf[sel][c0 * ZS + wcol]) =
            pack4bf(z[0], z[1], z[2], z[3]);
        __syncthreads();
        // B-operand: z^T frag — lane n=c0 (batch row), k=8q+j. Identical
        // addressing to the pre-swap A-frag read.
        const s8 b0 = *reinterpret_cast<const s8*>(&zbuf[sel][c0 * ZS + 8 * q]);
        const s8 b1 = *reinterpret_cast<const s8*>(&zbuf[sel][c0 * ZS + 8 * q + 32]);
        // Two independent MFMA chains (overlapped latency), then one add.
        f4 acc0 = __builtin_amdgcn_mfma_f32_16x16x32_bf16(whi[0], b0, xf,   0, 0, 0);
        f4 acc1 = __builtin_amdgcn_mfma_f32_16x16x32_bf16(whi[1], b1, zero, 0, 0, 0);
#pragma unroll
        for (int i = 0; i < 4; ++i) z[i] = tanh_pre(acc0[i] + acc1[i]);
    }

    // ---- phase 2: split-precision polish (fp32-grade): zl = Wh.Ah + Wh.Al
    // + Wl.Ah, dropping only Wl.Al ~ 3e-8. One barrier per polish. Buffer
    // parity: N_BF16 is ODD, so polish p uses buffer (N_BF16+p)&1 — polish 0
    // must NOT write zbuf[0] (apply N_BF16-1's reads of zbuf[0] may still be
    // in flight in other waves). Three independent 2-deep MFMA chains.
    for (int p = 0; p < N_POL; ++p) {
        const int sel2 = (N_BF16 + p) & 1;
        {
            s4 hi4, lo4;
#pragma unroll
            for (int i = 0; i < 4; ++i) {
                const unsigned short hb = f2bf(z[i]);
                hi4[i] = (short)hb;
                lo4[i] = (short)f2bf(z[i] - bf2f(hb));
            }
            *reinterpret_cast<s4*>(&zbuf[sel2][c0 * ZS + wcol]) = hi4;
            *reinterpret_cast<s4*>(&zLo[sel2][c0 * ZS + wcol])  = lo4;
        }
        __syncthreads();
        const s8 bh0 = *reinterpret_cast<const s8*>(&zbuf[sel2][c0 * ZS + 8 * q]);
        const s8 bh1 = *reinterpret_cast<const s8*>(&zbuf[sel2][c0 * ZS + 8 * q + 32]);
        const s8 bl0 = *reinterpret_cast<const s8*>(&zLo[sel2][c0 * ZS + 8 * q]);
        const s8 bl1 = *reinterpret_cast<const s8*>(&zLo[sel2][c0 * ZS + 8 * q + 32]);
        // chain A: Wh0.Ah0 + x -> + Wh0.Al0        (2 deep)
        f4 cA = __builtin_amdgcn_mfma_f32_16x16x32_bf16(whi[0], bh0, xf,   0, 0, 0);
        // chain B: Wh1.Ah1     -> + Wh1.Al1        (2 deep)
        f4 cB = __builtin_amdgcn_mfma_f32_16x16x32_bf16(whi[1], bh1, zero, 0, 0, 0);
        // chain C: Wl0.Ah0     -> + Wl1.Ah1        (2 deep)
        f4 cC = __builtin_amdgcn_mfma_f32_16x16x32_bf16(wlo[0], bh0, zero, 0, 0, 0);
        cA = __builtin_amdgcn_mfma_f32_16x16x32_bf16(whi[0], bl0, cA, 0, 0, 0);
        cB = __builtin_amdgcn_mfma_f32_16x16x32_bf16(whi[1], bl1, cB, 0, 0, 0);
        cC = __builtin_amdgcn_mfma_f32_16x16x32_bf16(wlo[1], bh1, cC, 0, 0, 0);
#pragma unroll
        for (int i = 0; i < 4; ++i) z[i] = tanh_pre(cA[i] + cB[i] + cC[i]);
    }

    // ---- store: lane holds batch row c0, cols wcol..wcol+3 -> one float4.
    {
        float4 o;
        o.x = z[0]; o.y = z[1]; o.z = z[2]; o.w = z[3];
        *reinterpret_cast<float4*>(out + (r0 + c0) * DD + wcol) = o;
    }
}

extern "C" void kernel_launch(void* const* d_in, const int* in_sizes, int n_in,
                              void* d_out, int out_size, void* d_ws, size_t ws_size,
                              hipStream_t stream)
{
    const float* x = (const float*)d_in[0];   // [B, 64] fp32
    const float* W = (const float*)d_in[1];   // [64, 64] fp32
    float* out     = (float*)d_out;           // [B, 64] fp32
    const int B = in_sizes[0] / DD;           // 4096
    tanh_newton_mfma<<<B / RPB, 256, 0, stream>>>(x, W, out);
}